// Round 10
// baseline (111.954 us; speedup 1.0000x reference)
//
#include <hip/hip_runtime.h>
#include <hip/hip_bf16.h>

typedef __bf16 bf8_t __attribute__((ext_vector_type(8)));
typedef float  f4_t  __attribute__((ext_vector_type(4)));
typedef float  f16_t __attribute__((ext_vector_type(16)));
typedef int    i4_t  __attribute__((ext_vector_type(4)));

constexpr int Bc = 2;
constexpr int Tc = 2048;
constexpr int Sc = 2048;
constexpr int Hc = 8;
constexpr int Dc = 64;
constexpr int BQ = 128;         // Q rows per block (4 waves x 32)
constexpr int BK = 32;          // keys per prep image
constexpr int nQB = Tc / BQ;    // 16
constexpr int NKT = Sc / BK;    // 64 key images per (b,h)
constexpr int NP  = nQB / 2;    // 8 qt-pairs per (b,h)
constexpr int NS  = 4;          // slices per pair -> grid 512
constexpr int TILE_H = 4096;    // halves per image: K 2048 + V 2048
constexpr int KH = 2048;        // K halves per 32-key image
constexpr int SLOT_H = 8192;    // ring slot [K0|K1|V0|V1] = 16 KB

__device__ __forceinline__ void g2l16(const void* g, void* l) {
    __builtin_amdgcn_global_load_lds(
        (const __attribute__((address_space(1))) void*)g,
        (__attribute__((address_space(3))) void*)l, 16, 0, 0);
}

__device__ __forceinline__ int pack_bf16(float lo, float hi) {
    const unsigned l16 = (unsigned)__builtin_bit_cast(unsigned short, (__bf16)lo);
    const unsigned h16 = (unsigned)__builtin_bit_cast(unsigned short, (__bf16)hi);
    return (int)(l16 | (h16 << 16));
}

// key permutation rho (involution): swaps quarters 1<->2 of each 16-block.
__device__ __forceinline__ int rho(int pos) {
    const int t = (pos >> 2) & 3;
    return pos + (t == 1 ? 4 : (t == 2 ? -4 : 0));
}

// Kernel 0: fp32->bf16 convert into per-32-key 8KB images:
//   K:  key s row-major 32x64, octet swizzle ((d>>3) ^ (s&7))       (2048 halves)
//   V~: key-permuted (rho) transposed fat-row layout:
//       element (d, pos) at (d>>2)*128 + ((((d&3)<<2)|(pos>>3)) ^ ((d>>2)&15))*8
//       + (pos&7), holding V[rho(pos)][d]                           (2048 halves)
// plus per-image 32-bit key-padding-mask words.
__global__ __launch_bounds__(256)
void fa_prep(const float* __restrict__ kv, const int* __restrict__ kpm,
             __bf16* __restrict__ kvb, unsigned* __restrict__ kpmw)
{
    const int idx    = blockIdx.x * 256 + threadIdx.x;   // 0..524287
    const int tile   = idx >> 9;                         // (b*8+h)*64 + s32
    const int within = idx & 511;                        // 16B chunk in tile
    const int b  = tile >> 9;
    const int h  = (tile >> 6) & 7;
    const int s0 = (tile & 63) * BK;
    bf8_t o;
    __bf16* dst;
    if (within < 256) {                                  // K region (swizzled)
        const int row = within >> 3;                     // key in tile
        const int col = ((within & 7) * 8) ^ ((row & 7) << 3);
        const float* src = kv + (((size_t)(b * Sc + s0 + row) * 2 + 0) * Hc + h) * Dc + col;
        const float4 x0 = *(const float4*)src;
        const float4 x1 = *(const float4*)(src + 4);
        o[0] = (__bf16)x0.x; o[1] = (__bf16)x0.y; o[2] = (__bf16)x0.z; o[3] = (__bf16)x0.w;
        o[4] = (__bf16)x1.x; o[5] = (__bf16)x1.y; o[6] = (__bf16)x1.z; o[7] = (__bf16)x1.w;
        dst = kvb + (size_t)tile * TILE_H + within * 8;
    } else {                                             // V region (rho-permuted)
        const int c  = within - 256;
        const int d  = c >> 2;                           // 0..63
        const int g8 = c & 3;                            // position octet
        const float* vbase = kv + (((size_t)(b * Sc + s0) * 2 + 1) * Hc + h) * Dc + d;
        #pragma unroll
        for (int j = 0; j < 8; ++j) {
            const int key = rho(g8 * 8 + j);
            o[j] = (__bf16)vbase[(size_t)key * 2 * Hc * Dc];
        }
        const int slot = (((d & 3) << 2) | g8) ^ ((d >> 2) & 15);
        dst = kvb + (size_t)tile * TILE_H + KH + (d >> 2) * 128 + slot * 8;
    }
    *(bf8_t*)dst = o;

    if (idx < Bc * NKT) {                                // pack kpm bits per image
        const int bb = idx >> 6, tt = idx & 63;
        unsigned m = 0;
        for (int k = 0; k < 32; ++k)
            m |= (kpm[bb * Sc + tt * BK + k] != 0 ? 1u : 0u) << k;
        kpmw[idx] = m;
    }
}

// Kernel 1: 32x32x16-MFMA flash attention. 4 waves x 32 queries = 128q/block;
// each wave consumes the full 64-key tile -> 64 ds_read_b128 and ZERO bpermute
// per 128q*64k block-iter (4x fewer LDS data ops than the 16x16 version: the
// measured bottleneck). Swapped QK^T (mfma(K,Q)): P C-layout col=query=lane&31,
// row=key=(reg&3)+8*(reg>>2)+4*hi; with V's keys rho-permuted in prep, the PV
// A-frag is pack(pv[8kc..8kc+7]) in register order for every lane -- no
// cross-lane exchange. qt-pairing (pair cost exactly 34 causal iters), NS=4,
// grid 512. One barrier per iter, vmcnt(0) at loop top (own loads a full
// iteration old). Fixed-max softmax (m=8) -> split partials are pure sums.
__global__ __launch_bounds__(256, 2)
void fa_part(const float* __restrict__ q,
             const __bf16* __restrict__ kvb,
             const unsigned* __restrict__ kpmw,
             const int* __restrict__ causal_p,
             float* __restrict__ part_o,
             float* __restrict__ part_l)
{
    __shared__ __bf16 shKV[2 * SLOT_H];      // 32 KB ring: 2 x [K0|K1|V0|V1]

    const int tid  = threadIdx.x;
    const int wave = tid >> 6;               // 0..3
    const int lane = tid & 63;
    const int qcol = lane & 31;              // query col / key row / d col
    const int hi   = lane >> 5;
    const int hi4  = hi * 4;

    // decode: h in low 3 bits (XCD locality); then b, pair p, slice s
    const int bid = blockIdx.x;
    const int h   = bid & 7;
    const int g   = bid >> 3;
    const int b   = g / (NP * NS);
    const int rem = g % (NP * NS);
    const int p   = rem / NS;
    const int s   = rem % NS;
    const int causal = causal_p[0];

    const int nA   = causal ? (32 - 2 * p) : 32;   // 64-key tiles for qA = 15-p
    const int nB   = causal ? (2 * p + 2)  : 32;   // 64-key tiles for qB = p
    const int ntot = nA + nB;                      // 34 causal / 64 full
    const int lo   = (ntot * s + NS - 1) / NS;
    const int hi_s = (ntot * (s + 1) + NS - 1) / NS;

    const __bf16* kvt = kvb + (size_t)((b * Hc + h) * NKT) * TILE_H;
    const unsigned* mw_b = kpmw + b * NKT;

    // loop-invariant LDS read offsets (halves)
    int kaddr[4];
    #pragma unroll
    for (int dc = 0; dc < 4; ++dc)
        kaddr[dc] = qcol * 64 + ((((2 * dc + hi) << 3)) ^ ((qcol & 7) << 3));
    int vaddr[2][2];
    #pragma unroll
    for (int kc = 0; kc < 2; ++kc)
        #pragma unroll
        for (int dg = 0; dg < 2; ++dg) {
            const int d    = dg * 32 + qcol;
            const int koct = kc * 2 + hi;
            const int r    = d >> 2;
            const int slot = (((d & 3) << 2) | koct) ^ (r & 15);
            vaddr[kc][dg]  = r * 128 + slot * 8;
        }
    const int c8 = tid * 8;                  // staging chunk (halves)
    const float scale = 0.125f;

    #pragma unroll 1
    for (int seg = 0; seg < 2; ++seg) {
        const int qt = seg ? p : (nQB - 1 - p);
        const int t0 = seg ? (max(lo, nA) - nA) : lo;
        const int t1 = seg ? (hi_s - nA)        : min(hi_s, nA);
        if (t0 >= t1) continue;

        __syncthreads();   // ring reuse across segments

        const int q_base = qt * BQ;
        const int tqn    = q_base + wave * 32 + qcol;  // this lane's query row

        // ---- Q fragments (B-layout: n=qcol, k(d)=dc*16+hi*8+j), scaled ----
        bf8_t a_q[4];
        {
            const float* qrow = q + ((size_t)(b * Tc + tqn) * Hc + h) * Dc;
            #pragma unroll
            for (int dc = 0; dc < 4; ++dc) {
                const float4 x0 = *(const float4*)(qrow + dc * 16 + hi * 8);
                const float4 x1 = *(const float4*)(qrow + dc * 16 + hi * 8 + 4);
                bf8_t v;
                v[0] = (__bf16)(x0.x * scale); v[1] = (__bf16)(x0.y * scale);
                v[2] = (__bf16)(x0.z * scale); v[3] = (__bf16)(x0.w * scale);
                v[4] = (__bf16)(x1.x * scale); v[5] = (__bf16)(x1.y * scale);
                v[6] = (__bf16)(x1.z * scale); v[7] = (__bf16)(x1.w * scale);
                a_q[dc] = v;
            }
        }

        f16_t o_acc[2];
        #pragma unroll
        for (int dg = 0; dg < 2; ++dg)
            #pragma unroll
            for (int i = 0; i < 16; ++i) o_acc[dg][i] = 0.f;
        float lsum = 0.f;

        int cu = 0;
        unsigned cm0, cm1;
        {   // prologue: stage first 64-key tile (4 regions), load masks
            const __bf16* src = kvt + (size_t)(2 * t0) * TILE_H;
            g2l16(src + c8,               &shKV[c8]);
            g2l16(src + TILE_H + c8,      &shKV[2048 + c8]);
            g2l16(src + KH + c8,          &shKV[4096 + c8]);
            g2l16(src + TILE_H + KH + c8, &shKV[6144 + c8]);
            cm0 = mw_b[2 * t0];
            cm1 = mw_b[2 * t0 + 1];
        }

        for (int it = t0; it < t1; ++it) {
            // own staged loads are a full iteration old -> vmcnt(0) ~free;
            // the barrier publishes all waves' staging + closes WAR window.
            asm volatile("s_waitcnt vmcnt(0)" ::: "memory");
            __builtin_amdgcn_s_barrier();

            const int nx = cu ^ SLOT_H;
            unsigned nm0 = 0, nm1 = 0;
            if (it + 1 < t1) {   // issue next tile; lands during compute
                const __bf16* srcn = kvt + (size_t)(2 * (it + 1)) * TILE_H;
                g2l16(srcn + c8,               &shKV[nx + c8]);
                g2l16(srcn + TILE_H + c8,      &shKV[nx + 2048 + c8]);
                g2l16(srcn + KH + c8,          &shKV[nx + 4096 + c8]);
                g2l16(srcn + TILE_H + KH + c8, &shKV[nx + 6144 + c8]);
                nm0 = mw_b[2 * it + 2];
                nm1 = mw_b[2 * it + 3];
            }

            const int kb = it * 64;
            #pragma unroll
            for (int kh = 0; kh < 2; ++kh) {
                const unsigned msk = (kh ? cm1 : cm0) >> hi4;
                // ---- swapped QK^T: S[key][query], 4 MFMAs over d ----
                f16_t sc;
                #pragma unroll
                for (int i = 0; i < 16; ++i) sc[i] = 0.f;
                #pragma unroll
                for (int dc = 0; dc < 4; ++dc) {
                    const bf8_t bk = *(const bf8_t*)&shKV[cu + kh * 2048 + kaddr[dc]];
                    sc = __builtin_amdgcn_mfma_f32_32x32x16_bf16(bk, a_q[dc], sc, 0, 0, 0);
                }
                // ---- fixed-max softmax (m=8), per-reg masks ----
                float pv[16];
                #pragma unroll
                for (int r = 0; r < 16; ++r) {
                    const int krow = (r & 3) + 8 * (r >> 2);
                    const int key  = kb + kh * 32 + krow + hi4;
                    const bool valid = ((msk >> krow) & 1u) && (!causal || key <= tqn);
                    const float pp = valid ? __expf(sc[r] - 8.0f) : 0.0f;
                    lsum += pp;
                    pv[r] = pp;
                }
                // ---- PV A-frags: pure in-register pack (rho absorbs layout) ----
                union { i4_t i; bf8_t v; } ua, ub;
                #pragma unroll
                for (int r2 = 0; r2 < 4; ++r2) {
                    ua.i[r2] = pack_bf16(pv[2 * r2],     pv[2 * r2 + 1]);
                    ub.i[r2] = pack_bf16(pv[8 + 2 * r2], pv[9 + 2 * r2]);
                }
                // ---- PV: 4 MFMAs (kc x dg) with V from LDS ----
                #pragma unroll
                for (int dg = 0; dg < 2; ++dg) {
                    const int vbase = cu + 4096 + kh * 2048;
                    const bf8_t bv0 = *(const bf8_t*)&shKV[vbase + vaddr[0][dg]];
                    o_acc[dg] = __builtin_amdgcn_mfma_f32_32x32x16_bf16(ua.v, bv0, o_acc[dg], 0, 0, 0);
                    const bf8_t bv1 = *(const bf8_t*)&shKV[vbase + vaddr[1][dg]];
                    o_acc[dg] = __builtin_amdgcn_mfma_f32_32x32x16_bf16(ub.v, bv1, o_acc[dg], 0, 0, 0);
                }
            }
            cm0 = nm0; cm1 = nm1; cu = nx;
        }

        // ---- l: lane and lane^32 hold same query, disjoint keys ----
        lsum += __shfl_xor(lsum, 32);

        // ---- write partial: slot = (((b*8+h)*NP + p)*NS + s)*2 + seg ----
        const size_t slot = (size_t)(((b * Hc + h) * NP + p) * NS + s) * 2 + seg;
        float* po = part_o + slot * (BQ * Dc);
        #pragma unroll
        for (int dg = 0; dg < 2; ++dg)
            #pragma unroll
            for (int r = 0; r < 16; ++r) {
                const int row = wave * 32 + (r & 3) + 8 * (r >> 2) + hi4;
                po[row * Dc + dg * 32 + qcol] = o_acc[dg][r];
            }
        if (hi == 0)
            part_l[slot * BQ + wave * 32 + qcol] = lsum;
    }
}

// Kernel 2: gather the (slice,seg) partials that touched this qt, sum,
// normalize, scatter to out layout. Predicate mirrors the writer's exactly.
__global__ __launch_bounds__(256, 4)
void fa_reduce(const float* __restrict__ part_o,
               const float* __restrict__ part_l,
               const int* __restrict__ causal_p,
               float* __restrict__ out)
{
    const int gtid = blockIdx.x * 256 + threadIdx.x;     // one float4 each
    const int e    = gtid & (BQ * Dc / 4 - 1);           // 0..2047
    const int qi   = gtid >> 11;
    const int row  = e >> 4;                             // 0..127
    const int d4   = e & 15;

    const int qt = qi & (nQB - 1);                       // 0..15
    const int h  = (qi >> 4) & (Hc - 1);
    const int b  = qi >> 7;
    const int causal = causal_p[0];

    const int p    = (qt < NP) ? qt : (nQB - 1 - qt);
    const int seg  = (qt < NP) ? 1 : 0;
    const int nA   = causal ? (32 - 2 * p) : 32;
    const int nB   = causal ? (2 * p + 2)  : 32;
    const int ntot = nA + nB;
    const int segLo = seg ? nA : 0;
    const int segHi = seg ? ntot : nA;

    float4 acc = make_float4(0.f, 0.f, 0.f, 0.f);
    float  l   = 0.f;
    #pragma unroll
    for (int s = 0; s < NS; ++s) {
        const int lo = (ntot * s + NS - 1) / NS;
        const int hi = (ntot * (s + 1) + NS - 1) / NS;
        if (lo < segHi && segLo < hi && lo < hi) {
            const size_t slot = (size_t)(((b * Hc + h) * NP + p) * NS + s) * 2 + seg;
            const float4 v = *(const float4*)(part_o + slot * (BQ * Dc) + row * Dc + d4 * 4);
            acc.x += v.x; acc.y += v.y; acc.z += v.z; acc.w += v.w;
            l += part_l[slot * BQ + row];
        }
    }
    const float inv = 1.0f / l;
    const int t = qt * BQ + row;
    float4 o;
    o.x = acc.x * inv; o.y = acc.y * inv; o.z = acc.z * inv; o.w = acc.w * inv;
    *(float4*)(out + ((size_t)(b * Tc + t) * Hc + h) * Dc + d4 * 4) = o;
}

extern "C" void kernel_launch(void* const* d_in, const int* in_sizes, int n_in,
                              void* d_out, int out_size, void* d_ws, size_t ws_size,
                              hipStream_t stream) {
    const float* q   = (const float*)d_in[0];
    const float* kv  = (const float*)d_in[1];
    const int*   kpm = (const int*)d_in[2];
    const int*   cz  = (const int*)d_in[3];
    float*       out = (float*)d_out;

    __bf16* kvb = (__bf16*)d_ws;
    const size_t kvb_bytes = (size_t)Bc * Hc * NKT * TILE_H * sizeof(__bf16); // 8 MB
    unsigned* kpmw = (unsigned*)((char*)d_ws + kvb_bytes);
    float* part_o  = (float*)((char*)d_ws + kvb_bytes + 4096);

    const size_t nslots = (size_t)Bc * Hc * NP * NS * 2;      // 1024
    float* part_l = part_o + nslots * (BQ * Dc);              // ~34 MB total

    const int grid0 = Bc * Hc * NKT * 512 / 256;              // 2048
    fa_prep<<<grid0, 256, 0, stream>>>(kv, kpm, kvb, kpmw);

    const int grid1 = Bc * Hc * NP * NS;                      // 512 = 2/CU
    fa_part<<<grid1, 256, 0, stream>>>(q, kvb, kpmw, cz, part_o, part_l);

    const int grid2 = (int)((size_t)Bc * Hc * nQB * (BQ * Dc / 4) / 256); // 2048
    fa_reduce<<<grid2, 256, 0, stream>>>(part_o, part_l, cz, out);
}